// Round 2
// baseline (266.309 us; speedup 1.0000x reference)
//
#include <hip/hip_runtime.h>

// WaveletParsingLayer: per-row stable stream compaction.
// x3[B,C,L] -> out[B,C,KEEP], dropping elements == FILLER (10.1f), order-preserving.
// x1, x2 are unused by the reference.
//
// R6: R5 counters: kernel 79us at 26.5% HBM, VALUBusy 16%, conflicts ~3% —
// no pipe saturated. Roofline floor ~36us. Diagnosis: barrier-convoyed
// burst-idle-burst memory pattern (all 3 resident blocks sit in the
// memory-idle prefix/scatter phase together). Fix: software-pipeline TWO
// rows per block — both rows' global loads issued up front, so row1's HBM
// latency hides under row0's LDS phases. Same 48KB stage (serial reuse),
// same 3 blocks/CU, still 2 barriers per row.

#define FILLER_VAL 10.1f
constexpr int L_LEN    = 16384;
constexpr int KEEP_LEN = 12288;
constexpr int BLOCK    = 512;           // 8 waves of 64
constexpr int NW       = BLOCK / 64;    // waves per block = 8
constexpr int CHUNK    = BLOCK * 4;     // 2048 elements per chunk
constexpr int NC       = L_LEN / CHUNK; // 8 chunks per row

struct RowState {
    float4 v[NC];
    int before[NC];
    int b0[NC], b1[NC], b2[NC];   // per-lane survivor bits (compiler keeps masks in SGPR)
};

__device__ __forceinline__ void load_row(RowState& s, const float* __restrict__ in, int tid)
{
    #pragma unroll
    for (int c = 0; c < NC; ++c)
        s.v[c] = *reinterpret_cast<const float4*>(in + c * CHUNK + tid * 4);
}

__device__ __forceinline__ void ballot_row(RowState& s, int lane, int wid,
                                           unsigned long long lt, int (*wtot)[NW])
{
    #pragma unroll
    for (int c = 0; c < NC; ++c) {
        unsigned long long m0 = __ballot(s.v[c].x != FILLER_VAL);
        unsigned long long m1 = __ballot(s.v[c].y != FILLER_VAL);
        unsigned long long m2 = __ballot(s.v[c].z != FILLER_VAL);
        unsigned long long m3 = __ballot(s.v[c].w != FILLER_VAL);
        s.before[c] = __popcll(m0 & lt) + __popcll(m1 & lt)
                    + __popcll(m2 & lt) + __popcll(m3 & lt);
        s.b0[c] = (int)((m0 >> lane) & 1ULL);
        s.b1[c] = (int)((m1 >> lane) & 1ULL);
        s.b2[c] = (int)((m2 >> lane) & 1ULL);
        if (lane == 0)
            wtot[c][wid] = __popcll(m0) + __popcll(m1)
                         + __popcll(m2) + __popcll(m3);
    }
}

__device__ __forceinline__ void scatter_row(const RowState& s, int wid,
                                            float* stage, const int (*wtot)[NW])
{
    int run = 0;
    #pragma unroll
    for (int c = 0; c < NC; ++c) {
        int wb = run;
        #pragma unroll
        for (int w = 0; w < NW; ++w) {
            int t = wtot[c][w];
            if (w < wid) wb += t;
            run += t;
        }
        const int p0 = wb + s.before[c];
        const int p1 = p0 + s.b0[c];
        const int p2 = p1 + s.b1[c];
        const int p3 = p2 + s.b2[c];
        if (s.v[c].x != FILLER_VAL && p0 < KEEP_LEN) stage[p0] = s.v[c].x;
        if (s.v[c].y != FILLER_VAL && p1 < KEEP_LEN) stage[p1] = s.v[c].y;
        if (s.v[c].z != FILLER_VAL && p2 < KEEP_LEN) stage[p2] = s.v[c].z;
        if (s.v[c].w != FILLER_VAL && p3 < KEEP_LEN) stage[p3] = s.v[c].w;
    }
}

__device__ __forceinline__ void copyout_row(const float* stage, float* __restrict__ o, int tid)
{
    #pragma unroll
    for (int k = 0; k < KEEP_LEN / (BLOCK * 4); ++k) {
        const int idx = (k * BLOCK + tid) * 4;
        *reinterpret_cast<float4*>(&o[idx]) =
            *reinterpret_cast<const float4*>(&stage[idx]);
    }
}

__global__ __launch_bounds__(BLOCK, 6) void compact_rows_kernel(
    const float* __restrict__ x3, float* __restrict__ out, int rows)
{
    const int row0 = blockIdx.x * 2;
    const int row1 = row0 + 1;
    const bool has1 = (row1 < rows);   // block-uniform

    const int tid  = threadIdx.x;
    const int lane = tid & 63;
    const int wid  = tid >> 6;
    const unsigned long long lt = (1ULL << lane) - 1ULL;

    __shared__ float stage[KEEP_LEN];   // 48 KB survivor staging (serially reused)
    __shared__ int wtot[NC][NW];        // per-chunk per-wave survivor counts

    RowState s0, s1;

    // ---- Issue BOTH rows' loads up front: row1's HBM latency hides under
    //      row0's prefix/scatter/copyout LDS phases.
    load_row(s0, x3 + (size_t)row0 * L_LEN, tid);
    if (has1) load_row(s1, x3 + (size_t)row1 * L_LEN, tid);

    // ---- Row 0 pipeline.
    ballot_row(s0, lane, wid, lt, wtot);
    __syncthreads();                    // b1: wtot(row0) visible
    scatter_row(s0, wid, stage, wtot);
    __syncthreads();                    // b2: stage(row0) complete
    copyout_row(stage, out + (size_t)row0 * KEEP_LEN, tid);

    // ---- Row 1 ballots overlap row0 copyout issue (wtot reuse is safe: its
    //      row0 readers all finished before b2).
    if (has1) ballot_row(s1, lane, wid, lt, wtot);
    __syncthreads();                    // b3: copyout(row0) LDS reads done + wtot(row1) visible
    if (has1) {
        scatter_row(s1, wid, stage, wtot);
    }
    __syncthreads();                    // b4: stage(row1) complete
    if (has1) copyout_row(stage, out + (size_t)row1 * KEEP_LEN, tid);
}

extern "C" void kernel_launch(void* const* d_in, const int* in_sizes, int n_in,
                              void* d_out, int out_size, void* d_ws, size_t ws_size,
                              hipStream_t stream)
{
    // in order: x1 [B,C,4096] f32 (unused), x2 [B,C,4096] f32 (unused),
    //           x3 [B,C,L] f32, keep_len (scalar int, value 12288)
    const float* x3 = (const float*)d_in[2];
    float* out = (float*)d_out;

    const int rows = in_sizes[2] / L_LEN;  // B*C = 2048
    const int grid = (rows + 1) / 2;

    compact_rows_kernel<<<grid, BLOCK, 0, stream>>>(x3, out, rows);
}